// Round 1
// baseline (78.809 us; speedup 1.0000x reference)
//
#include <hip/hip_runtime.h>
#include <stdint.h>

typedef _Float16 h2 __attribute__((ext_vector_type(2)));
typedef _Float16 h8 __attribute__((ext_vector_type(8)));
typedef float f32x4 __attribute__((ext_vector_type(4)));
typedef unsigned int u32;
typedef unsigned short u16;

// LDS strides (elements of the buffer's type)
#define PJ_STR 68    // pjT  [n*64+j][h]   u16 ; 136B rows
#define PI_STR 36    // sPi  [n][i<8][h2]  u32 ; 144B rows
#define CB_STR 72    // cb   [j=64][h]     u16 ; 144B rows
#define CT_STR 68    // ct   [h=64][j]     u16 ; 136B rows
#define AB_STR 72    // ab   [m=32][j]     u16 ; 144B rows
#define CS_STR 264   // cs   [i=16][c2]    u16 ; 528B rows (rows 8..15 zero pad)

__device__ __forceinline__ u32 pk2(float a, float b) {
    return __builtin_bit_cast(u32, __builtin_amdgcn_cvt_pkrtz(a, b));
}
__device__ __forceinline__ h8 frag4(u32 a, u32 b, u32 c, u32 d) {
    return __builtin_bit_cast(h8, make_uint4(a, b, c, d));
}

// ---------------- prep: pack weights as f16 fragments into workspace ----------------
// wpk layout (u32): [0, 8192)     WaT [c'=256][hh=32]  rows c' = n*64 + h_out
//                   [8192, 16384) WpT [o=64][cc=128]
//                   [16384,16512) ws  [n=4][hh=32]
__global__ __launch_bounds__(256) void pack_weights(
    const float* __restrict__ Wa_pair,
    const float* __restrict__ Wa_score,
    const float* __restrict__ W_proj,
    u32* __restrict__ wpk)
{
    const int g = blockIdx.x * 256 + threadIdx.x;   // 0..4095
    u32 v[4];
    if (g < 2048) {        // WaT: 8192 u32
        #pragma unroll
        for (int k = 0; k < 4; ++k) {
            const int idx = g * 4 + k;
            const int cp = idx >> 5, hh = idx & 31;
            const int c = (cp & 63) * 4 + (cp >> 6);        // c' = (c&3)*64 + (c>>2)
            v[k] = pk2(Wa_pair[(2 * hh) * 256 + c], Wa_pair[(2 * hh + 1) * 256 + c]);
        }
        *(uint4*)(wpk + g * 4) = make_uint4(v[0], v[1], v[2], v[3]);
    } else {               // WpT: 8192 u32
        #pragma unroll
        for (int k = 0; k < 4; ++k) {
            const int idx = (g - 2048) * 4 + k;
            const int o = idx >> 7, cc = idx & 127;
            v[k] = pk2(W_proj[(2 * cc) * 64 + o], W_proj[(2 * cc + 1) * 64 + o]);
        }
        *(uint4*)(wpk + 8192 + (g - 2048) * 4) = make_uint4(v[0], v[1], v[2], v[3]);
    }
    if (g < 128) {         // ws packed+transposed
        const int n = g & 3, hh = g >> 2;
        wpk[16384 + n * 32 + hh] =
            pk2(Wa_score[(2 * hh) * 4 + n], Wa_score[(2 * hh + 1) * 4 + n]);
    }
}

// ---------------- main kernel: 8 i-rows per block, 70.4 KB LDS -> 2 blocks/CU ----------------
__global__ __launch_bounds__(512, 4) void atom_attn(
    const float* __restrict__ inputs,
    const int*   __restrict__ scope,
    const u32*   __restrict__ wpk,
    float* __restrict__ out_mol,    // [64][64]
    float* __restrict__ out_flat)   // [N+1][64]
{
    __shared__ __align__(16) u16 s_pj[256 * PJ_STR];     // 34,816 B
    __shared__ __align__(16) u32 s_pi[4 * 8 * PI_STR];   //  4,608 B
    __shared__ __align__(16) u16 s_cb[64 * CB_STR];      //  9,216 B
    __shared__ __align__(16) u16 s_ct[64 * CT_STR];      //  8,704 B
    __shared__ __align__(16) u16 s_ab[32 * AB_STR];      //  4,608 B
    __shared__ __align__(16) u16 s_cs[16 * CS_STR];      //  8,448 B
    // total 70,400 B -> 2 blocks/CU

    const u32* __restrict__ waT = wpk;
    const u32* __restrict__ wpT = wpk + 8192;
    const u32* __restrict__ wsg = wpk + 16384;

    const int t = threadIdx.x;
    const int w = t >> 6, l = t & 63;
    const int ml = l & 15, q = l >> 4;
    const int b = blockIdx.y, bx = blockIdx.x;   // bx 0..7
    const int i_base = bx * 8;

    // -------- Phase 1 A-fragments: prefetch from packed global BEFORE the barrier --------
    const int mq = w & 3, jh = w >> 2;
    uint4 afr[4][2];
    #pragma unroll
    for (int k = 0; k < 4; ++k)
        #pragma unroll
        for (int ks = 0; ks < 2; ++ks)
            afr[k][ks] = *(const uint4*)(waT + ((mq * 4 + k) * 16 + ml) * 32 + ks * 16 + q * 4);

    // ================= Phase 0: stage c rows (cb + ct), zero cs pad rows =================
    if (t < 256) {
        const int jp = (t & 31) * 2;
        const int pp = t >> 5;           // h-octant 0..7
        const int r0 = scope[b * 64 + jp];
        const int r1 = scope[b * 64 + jp + 1];
        const f32x4 a0 = *(const f32x4*)(inputs + (size_t)r0 * 64 + pp * 8);
        const f32x4 a1 = *(const f32x4*)(inputs + (size_t)r0 * 64 + pp * 8 + 4);
        const f32x4 b0 = *(const f32x4*)(inputs + (size_t)r1 * 64 + pp * 8);
        const f32x4 b1 = *(const f32x4*)(inputs + (size_t)r1 * 64 + pp * 8 + 4);
        float A[8] = {a0[0], a0[1], a0[2], a0[3], a1[0], a1[1], a1[2], a1[3]};
        float B[8] = {b0[0], b0[1], b0[2], b0[3], b1[0], b1[1], b1[2], b1[3]};
        *(uint4*)&s_cb[jp * CB_STR + pp * 8] =
            make_uint4(pk2(A[0], A[1]), pk2(A[2], A[3]), pk2(A[4], A[5]), pk2(A[6], A[7]));
        *(uint4*)&s_cb[(jp + 1) * CB_STR + pp * 8] =
            make_uint4(pk2(B[0], B[1]), pk2(B[2], B[3]), pk2(B[4], B[5]), pk2(B[6], B[7]));
        #pragma unroll
        for (int e = 0; e < 8; ++e)
            *(u32*)&s_ct[(pp * 8 + e) * CT_STR + jp] = pk2(A[e], B[e]);
    }
    {   // zero cs rows 8..15 (phase-4 A-tile pad): 1056 u32
        u32* z = (u32*)(s_cs + 8 * CS_STR);
        for (int idx = t; idx < 1056; idx += 512) z[idx] = 0;
    }
    __syncthreads();

    // ================= Phase 1: P^T = WaT @ c^T (M=256 c', N=64 j, K=64 h) =================
    {
        f32x4 D[4][2];
        #pragma unroll
        for (int k = 0; k < 4; ++k) { D[k][0] = (f32x4)0.f; D[k][1] = (f32x4)0.f; }
        h8 bf[2][2];
        #pragma unroll
        for (int jt = 0; jt < 2; ++jt)
            #pragma unroll
            for (int ks = 0; ks < 2; ++ks)
                bf[jt][ks] = __builtin_bit_cast(h8,
                    *(const uint4*)&s_cb[((jh * 2 + jt) * 16 + ml) * CB_STR + ks * 32 + q * 8]);
        #pragma unroll
        for (int k = 0; k < 4; ++k) {
            #pragma unroll
            for (int ks = 0; ks < 2; ++ks) {
                const h8 af = __builtin_bit_cast(h8, afr[k][ks]);
                D[k][0] = __builtin_amdgcn_mfma_f32_16x16x32_f16(af, bf[0][ks], D[k][0], 0, 0, 0);
                D[k][1] = __builtin_amdgcn_mfma_f32_16x16x32_f16(af, bf[1][ks], D[k][1], 0, 0, 0);
            }
        }
        // store P^T; this block's 8 P_i rows also go to s_pi
        #pragma unroll
        for (int k = 0; k < 4; ++k) {
            const int mt = mq * 4 + k;
            const int nb = mt >> 2, h0 = (mt & 3) * 16 + q * 4;
            #pragma unroll
            for (int jt = 0; jt < 2; ++jt) {
                const int jtile = jh * 2 + jt;
                const int j = jtile * 16 + ml;
                const u32 p0 = pk2(D[k][jt][0], D[k][jt][1]);
                const u32 p1 = pk2(D[k][jt][2], D[k][jt][3]);
                *(uint2*)&s_pj[(nb * 64 + j) * PJ_STR + h0] = make_uint2(p0, p1);
                if (jtile == (bx >> 1) && ((ml >> 3) == (bx & 1)))
                    *(uint2*)&s_pi[(nb * 8 + (ml & 7)) * PI_STR + (h0 >> 1)] = make_uint2(p0, p1);
            }
        }
    }
    __syncthreads();

    // ================= Phase 2: scores (wave = (n, i-half), lane = j) =================
    {
        const int n = w & 3, ih = w >> 2;
        u32 pj_u[32];
        #pragma unroll
        for (int k = 0; k < 16; ++k) {
            const uint2 vv = *(const uint2*)&s_pj[(n * 64 + l) * PJ_STR + k * 4];
            pj_u[2 * k] = vv.x; pj_u[2 * k + 1] = vv.y;
        }
        u32 ws_u[32];
        #pragma unroll
        for (int k = 0; k < 8; ++k) {
            const uint4 vv = *(const uint4*)(wsg + n * 32 + k * 4);
            ws_u[4 * k] = vv.x; ws_u[4 * k + 1] = vv.y;
            ws_u[4 * k + 2] = vv.z; ws_u[4 * k + 3] = vv.w;
        }
        const h2 zero2 = {(_Float16)0.f, (_Float16)0.f};
        #pragma unroll
        for (int ii = 0; ii < 4; ++ii) {
            const int iloc = ih * 4 + ii;
            const u32* pir = &s_pi[(n * 8 + iloc) * PI_STR];
            float s0 = 0.f, s1 = 0.f;
            #pragma unroll
            for (int c8 = 0; c8 < 8; ++c8) {
                const uint4 pv = *(const uint4*)&pir[c8 * 4];
                const u32 pe[4] = {pv.x, pv.y, pv.z, pv.w};
                #pragma unroll
                for (int e = 0; e < 4; ++e) {
                    const h2 pi2 = __builtin_bit_cast(h2, pe[e]);
                    const h2 pj2 = __builtin_bit_cast(h2, pj_u[c8 * 4 + e]);
                    h2 tv = pi2 + pj2;                         // v_pk_add_f16
                    tv = __builtin_elementwise_max(tv, zero2); // v_pk_max_f16
                    if (e & 1)
                        s1 = __builtin_amdgcn_fdot2(tv,
                                __builtin_bit_cast(h2, ws_u[c8 * 4 + e]), s1, false);
                    else
                        s0 = __builtin_amdgcn_fdot2(tv,
                                __builtin_bit_cast(h2, ws_u[c8 * 4 + e]), s0, false);
                }
            }
            const float s = s0 + s1;
            const float a = 1.f / (1.f + __expf(-s));
            const _Float16 ah = (_Float16)a;
            s_ab[(iloc * 4 + n) * AB_STR + l] = __builtin_bit_cast(u16, ah);
        }
    }
    __syncthreads();

    // -------- Phase 4 B-fragments: prefetch from packed global, hide under phase 3 --------
    uint4 wfr[8];
    if (w < 4) {
        #pragma unroll
        for (int ks = 0; ks < 8; ++ks)
            wfr[ks] = *(const uint4*)(wpT + (w * 16 + ml) * 128 + ks * 16 + q * 4);
    }

    // ================= Phase 3: c_sum = ab @ c (M=32 m=(i,n), N=64 h, K=64 j) =================
    {
        const int mt3 = w & 1, nt = w >> 1;
        h8 af3[2];
        #pragma unroll
        for (int ks = 0; ks < 2; ++ks)
            af3[ks] = __builtin_bit_cast(h8,
                *(const uint4*)&s_ab[(mt3 * 16 + ml) * AB_STR + ks * 32 + q * 8]);
        f32x4 D2 = (f32x4)0.f;
        #pragma unroll
        for (int ks = 0; ks < 2; ++ks) {
            const uint2 y0 = *(const uint2*)&s_ct[(nt * 16 + ml) * CT_STR + ks * 32 + q * 8];
            const uint2 y1 = *(const uint2*)&s_ct[(nt * 16 + ml) * CT_STR + ks * 32 + q * 8 + 4];
            const h8 bfc = frag4(y0.x, y0.y, y1.x, y1.y);
            D2 = __builtin_amdgcn_mfma_f32_16x16x32_f16(af3[ks], bfc, D2, 0, 0, 0);
        }
        // D rows m = mt3*16 + q*4 + r -> iloc = mt3*4+q (0..7), n = r
        const int iloc = mt3 * 4 + q, h = nt * 16 + ml;
        *(uint2*)&s_cs[iloc * CS_STR + h * 4] =
            make_uint2(pk2(D2[0], D2[1]), pk2(D2[2], D2[3]));
    }
    __syncthreads();

    // ================= Phase 4: out = cs @ Wp (M=16 (8 pad), N=64 o, K=256), waves 0-3 =====
    if (w < 4) {
        f32x4 D4 = (f32x4)0.f;
        #pragma unroll
        for (int ks = 0; ks < 8; ++ks) {
            const h8 af = __builtin_bit_cast(h8,
                *(const uint4*)&s_cs[ml * CS_STR + ks * 32 + q * 8]);
            D4 = __builtin_amdgcn_mfma_f32_16x16x32_f16(af, __builtin_bit_cast(h8, wfr[ks]),
                                                        D4, 0, 0, 0);
        }
        const int o = w * 16 + ml;
        #pragma unroll
        for (int r = 0; r < 4; ++r) {
            const int iloc = q * 4 + r;
            if (iloc < 8) {
                const int row = scope[b * 64 + i_base + iloc];
                if (row > 0) out_flat[(size_t)row * 64 + o] = D4[r];
            }
        }
        float s4 = D4[0] + D4[1] + D4[2] + D4[3];   // rows 8..15 are zero -> safe
        s4 += __shfl_xor(s4, 16, 64);
        s4 += __shfl_xor(s4, 32, 64);
        if (l < 16) atomicAdd(out_mol + b * 64 + o, s4);
    }
}

extern "C" void kernel_launch(void* const* d_in, const int* in_sizes, int n_in,
                              void* d_out, int out_size, void* d_ws, size_t ws_size,
                              hipStream_t stream) {
    const float* inputs   = (const float*)d_in[0];
    const int*   scope    = (const int*)d_in[1];
    // d_in[2] = scope_rev (unused: flat row index == scope value)
    const float* Wa_pair  = (const float*)d_in[3];
    const float* Wa_score = (const float*)d_in[4];
    const float* W_proj   = (const float*)d_in[5];
    float* out = (float*)d_out;
    u32* wpk = (u32*)d_ws;    // 66,048 B used

    // zero only what isn't fully overwritten: out_mol [64*64] + flat row 0 [64]
    (void)hipMemsetAsync(d_out, 0, (64 * 64 + 64) * sizeof(float), stream);

    // pack weights once per launch (inputs may be re-poisoned between iterations)
    pack_weights<<<dim3(16), 256, 0, stream>>>(Wa_pair, Wa_score, W_proj, wpk);

    // (i-8-group, molecule): 512 blocks x 512 thr -> 2 blocks/CU, 16 waves/CU
    dim3 grid(8, 64);
    atom_attn<<<grid, 512, 0, stream>>>(inputs, scope, wpk, out, out + 64 * 64);
}

// Round 2
// 75.015 us; speedup vs baseline: 1.0506x; 1.0506x over previous
//
#include <hip/hip_runtime.h>
#include <stdint.h>

typedef _Float16 h2 __attribute__((ext_vector_type(2)));
typedef _Float16 h8 __attribute__((ext_vector_type(8)));
typedef float f32x4 __attribute__((ext_vector_type(4)));
typedef unsigned int u32;
typedef unsigned short u16;

// LDS strides (elements of the buffer's type)
#define CB_STR 72    // cb  [j=64][h]    u16 ; 144B rows (16B-aligned uint4 reads)
#define WA_STR 68    // waT [ho=64][h]   u16 ; 136B rows (uint2 reads)
#define WP_STR 68    // wpT [o=64][h]    u16 ; 136B rows
#define P_STR  68    // P   [atom][ho]   u16 ; 136B rows
#define CW_STR 68    // cwT [o=64][j]    u16 ; 136B rows
#define AB_STR 72    // ab  [i=64][j]    u16 ; 144B rows

__device__ __forceinline__ u32 pk2(float a, float b) {
    return __builtin_bit_cast(u32, __builtin_amdgcn_cvt_pkrtz(a, b));
}
__device__ __forceinline__ h8 frag4(u32 a, u32 b, u32 c, u32 d) {
    return __builtin_bit_cast(h8, make_uint4(a, b, c, d));
}

// block = (head n, molecule b): phase-1 work split by head -> zero grid-wide duplication.
// out[b,i,o] = sum_n sum_j att_n[i,j] * cw_n[j,o],  cw_n = c @ Wp_n  (fused projection)
__global__ __launch_bounds__(512, 1) void atom_attn(
    const float* __restrict__ inputs,
    const int*   __restrict__ scope,
    const float* __restrict__ Wa_pair,
    const float* __restrict__ Wa_score,
    const float* __restrict__ W_proj,
    float* __restrict__ out_mol,    // [64][64]
    float* __restrict__ out_flat)   // [N+1][64]
{
    __shared__ __align__(16) u16 s_cb[64 * CB_STR];   // 9,216 B  c[j][h]
    __shared__ __align__(16) u16 s_wa[64 * WA_STR];   // 8,704 B  waT_n[ho][h]
    __shared__ __align__(16) u16 s_wp[64 * WP_STR];   // 8,704 B  wpT_n[o][h]
    __shared__ __align__(16) u16 s_p [64 * P_STR ];   // 8,704 B  P_n[atom][ho]
    __shared__ __align__(16) u16 s_cw[64 * CW_STR];   // 8,704 B  cwT_n[o][j]
    __shared__ __align__(16) u16 s_ab[64 * AB_STR];   // 9,216 B  att_n[i][j]
    __shared__ __align__(16) u32 s_ws[32];            //   128 B  ws_n packed [h2]
    // total 53,376 B

    const int t = threadIdx.x;
    const int w = t >> 6, l = t & 63;
    const int ml = l & 15, q = l >> 4;
    const int n = blockIdx.x;   // head 0..3
    const int b = blockIdx.y;   // molecule 0..63

    // ================= Phase 0: stage c, waT_n, wpT_n, ws_n =================
    if (t < 256) {   // c rows -> cb [j][h] (f16 packed)
        const int jp = (t & 31) * 2;
        const int pp = t >> 5;           // h-octant 0..7
        const int r0 = scope[b * 64 + jp];
        const int r1 = scope[b * 64 + jp + 1];
        const f32x4 a0 = *(const f32x4*)(inputs + (size_t)r0 * 64 + pp * 8);
        const f32x4 a1 = *(const f32x4*)(inputs + (size_t)r0 * 64 + pp * 8 + 4);
        const f32x4 b0 = *(const f32x4*)(inputs + (size_t)r1 * 64 + pp * 8);
        const f32x4 b1 = *(const f32x4*)(inputs + (size_t)r1 * 64 + pp * 8 + 4);
        *(uint4*)&s_cb[jp * CB_STR + pp * 8] =
            make_uint4(pk2(a0[0], a0[1]), pk2(a0[2], a0[3]), pk2(a1[0], a1[1]), pk2(a1[2], a1[3]));
        *(uint4*)&s_cb[(jp + 1) * CB_STR + pp * 8] =
            make_uint4(pk2(b0[0], b0[1]), pk2(b0[2], b0[3]), pk2(b1[0], b1[1]), pk2(b1[2], b1[3]));
    }
    {   // waT_n[ho][h_in] = f16(Wa_pair[h_in][4*ho + n]); lane l -> ho, wave w -> h_in octet
        float a[8];
        #pragma unroll
        for (int e = 0; e < 8; ++e)
            a[e] = Wa_pair[(w * 8 + e) * 256 + 4 * l + n];
        *(uint4*)&s_wa[l * WA_STR + w * 8] =
            make_uint4(pk2(a[0], a[1]), pk2(a[2], a[3]), pk2(a[4], a[5]), pk2(a[6], a[7]));
    }
    {   // wpT_n[o][h] = f16(W_proj[h*4+n][o]); lane l -> o, wave w -> h octet (coalesced rows)
        u32 v[4];
        #pragma unroll
        for (int e = 0; e < 4; ++e) {
            const int hh = w * 4 + e;   // h pair (2hh, 2hh+1); c = h*4+n = 8hh+n / 8hh+4+n
            const float v0 = W_proj[(8 * hh + n) * 64 + l];
            const float v1 = W_proj[(8 * hh + 4 + n) * 64 + l];
            v[e] = pk2(v0, v1);
        }
        *(uint4*)&s_wp[l * WP_STR + w * 8] = make_uint4(v[0], v[1], v[2], v[3]);
    }
    if (t < 32) {   // ws_n packed pairs along ho
        s_ws[t] = pk2(Wa_score[(2 * t) * 4 + n], Wa_score[(2 * t + 1) * 4 + n]);
    }
    __syncthreads();

    // ================= Phase 1 (parallel): waves 0-3: P_n = waT_n @ c^T =================
    // =================                    waves 4-7: cw_n = c @ wpT_n^T =================
    if (w < 4) {
        // M = ho (tile w), N = j (4 tiles), K = h (2 halves). 8 MFMAs.
        f32x4 D[4];
        #pragma unroll
        for (int jt = 0; jt < 4; ++jt) D[jt] = (f32x4)0.f;
        #pragma unroll
        for (int ks = 0; ks < 2; ++ks) {
            const uint2 x0 = *(const uint2*)&s_wa[(w * 16 + ml) * WA_STR + ks * 32 + q * 8];
            const uint2 x1 = *(const uint2*)&s_wa[(w * 16 + ml) * WA_STR + ks * 32 + q * 8 + 4];
            const h8 af = frag4(x0.x, x0.y, x1.x, x1.y);
            #pragma unroll
            for (int jt = 0; jt < 4; ++jt) {
                const h8 bf = __builtin_bit_cast(h8,
                    *(const uint4*)&s_cb[(jt * 16 + ml) * CB_STR + ks * 32 + q * 8]);
                D[jt] = __builtin_amdgcn_mfma_f32_16x16x32_f16(af, bf, D[jt], 0, 0, 0);
            }
        }
        // store P as [atom][ho]: col j = jt*16+ml, rows ho = w*16 + q*4 + r (pk2 along ho)
        #pragma unroll
        for (int jt = 0; jt < 4; ++jt) {
            const int j = jt * 16 + ml;
            *(uint2*)&s_p[j * P_STR + w * 16 + q * 4] =
                make_uint2(pk2(D[jt][0], D[jt][1]), pk2(D[jt][2], D[jt][3]));
        }
    } else {
        // cw_n[j][o]: A[m=j][k=h] = cb rows, B[n=o][k=h] = wpT rows. M tile = w-4.
        const int w4 = w - 4;
        f32x4 D[4];
        #pragma unroll
        for (int ot = 0; ot < 4; ++ot) D[ot] = (f32x4)0.f;
        #pragma unroll
        for (int ks = 0; ks < 2; ++ks) {
            const h8 af = __builtin_bit_cast(h8,
                *(const uint4*)&s_cb[(w4 * 16 + ml) * CB_STR + ks * 32 + q * 8]);
            #pragma unroll
            for (int ot = 0; ot < 4; ++ot) {
                const uint2 y0 = *(const uint2*)&s_wp[(ot * 16 + ml) * WP_STR + ks * 32 + q * 8];
                const uint2 y1 = *(const uint2*)&s_wp[(ot * 16 + ml) * WP_STR + ks * 32 + q * 8 + 4];
                const h8 bf = frag4(y0.x, y0.y, y1.x, y1.y);
                D[ot] = __builtin_amdgcn_mfma_f32_16x16x32_f16(af, bf, D[ot], 0, 0, 0);
            }
        }
        // store cw^T as [o][j]: col o = ot*16+ml, rows j = w4*16 + q*4 + r (pk2 along j)
        #pragma unroll
        for (int ot = 0; ot < 4; ++ot) {
            const int o = ot * 16 + ml;
            *(uint2*)&s_cw[o * CW_STR + w4 * 16 + q * 4] =
                make_uint2(pk2(D[ot][0], D[ot][1]), pk2(D[ot][2], D[ot][3]));
        }
    }
    __syncthreads();

    // ================= Phase 2: scores; wave -> 8 i rows, lane -> j =================
    {
        u32 pj_u[32];
        #pragma unroll
        for (int k = 0; k < 16; ++k) {
            const uint2 vv = *(const uint2*)&s_p[l * P_STR + k * 4];
            pj_u[2 * k] = vv.x; pj_u[2 * k + 1] = vv.y;
        }
        u32 ws_u[32];
        #pragma unroll
        for (int k = 0; k < 8; ++k) {
            const uint4 vv = *(const uint4*)&s_ws[k * 4];
            ws_u[4 * k] = vv.x; ws_u[4 * k + 1] = vv.y;
            ws_u[4 * k + 2] = vv.z; ws_u[4 * k + 3] = vv.w;
        }
        const h2 zero2 = {(_Float16)0.f, (_Float16)0.f};
        #pragma unroll
        for (int ii = 0; ii < 8; ++ii) {
            const int i = w * 8 + ii;
            const u16* pir = &s_p[i * P_STR];   // uniform across lanes -> LDS broadcast
            float s0 = 0.f, s1 = 0.f;
            #pragma unroll
            for (int c8 = 0; c8 < 8; ++c8) {
                const uint2 u0 = *(const uint2*)&pir[c8 * 8];
                const uint2 u1 = *(const uint2*)&pir[c8 * 8 + 4];
                const u32 pe[4] = {u0.x, u0.y, u1.x, u1.y};
                #pragma unroll
                for (int e = 0; e < 4; ++e) {
                    const h2 pi2 = __builtin_bit_cast(h2, pe[e]);
                    const h2 pj2 = __builtin_bit_cast(h2, pj_u[c8 * 4 + e]);
                    h2 tv = pi2 + pj2;                         // v_pk_add_f16
                    tv = __builtin_elementwise_max(tv, zero2); // v_pk_max_f16
                    if (e & 1)
                        s1 = __builtin_amdgcn_fdot2(tv,
                                __builtin_bit_cast(h2, ws_u[c8 * 4 + e]), s1, false);
                    else
                        s0 = __builtin_amdgcn_fdot2(tv,
                                __builtin_bit_cast(h2, ws_u[c8 * 4 + e]), s0, false);
                }
            }
            const float s = s0 + s1;
            const float a = 1.f / (1.f + __expf(-s));
            const _Float16 ah = (_Float16)a;
            s_ab[i * AB_STR + l] = __builtin_bit_cast(u16, ah);
        }
    }
    __syncthreads();

    // ================= Phase 3: out_n = ab @ cw^T (M=64 i, N=64 o, K=64 j) =================
    {
        const int mt = w & 3, nh2 = w >> 2;
        h8 af3[2];
        #pragma unroll
        for (int ks = 0; ks < 2; ++ks)
            af3[ks] = __builtin_bit_cast(h8,
                *(const uint4*)&s_ab[(mt * 16 + ml) * AB_STR + ks * 32 + q * 8]);
        #pragma unroll
        for (int nx = 0; nx < 2; ++nx) {
            const int nt = nh2 * 2 + nx;
            f32x4 D = (f32x4)0.f;
            #pragma unroll
            for (int ks = 0; ks < 2; ++ks) {
                const uint2 y0 = *(const uint2*)&s_cw[(nt * 16 + ml) * CW_STR + ks * 32 + q * 8];
                const uint2 y1 = *(const uint2*)&s_cw[(nt * 16 + ml) * CW_STR + ks * 32 + q * 8 + 4];
                const h8 bf = frag4(y0.x, y0.y, y1.x, y1.y);
                D = __builtin_amdgcn_mfma_f32_16x16x32_f16(af3[ks], bf, D, 0, 0, 0);
            }
            const int o = nt * 16 + ml;
            float colsum = 0.f;
            #pragma unroll
            for (int r = 0; r < 4; ++r) {
                const int i = mt * 16 + q * 4 + r;
                const int row = scope[b * 64 + i];
                if (row > 0) atomicAdd(out_flat + (size_t)row * 64 + o, D[r]);
                colsum += D[r];   // pad i rows DO contribute to out_mol (matches reference)
            }
            colsum += __shfl_xor(colsum, 16, 64);
            colsum += __shfl_xor(colsum, 32, 64);
            if (q == 0) atomicAdd(out_mol + b * 64 + o, colsum);
        }
    }
}

extern "C" void kernel_launch(void* const* d_in, const int* in_sizes, int n_in,
                              void* d_out, int out_size, void* d_ws, size_t ws_size,
                              hipStream_t stream) {
    const float* inputs   = (const float*)d_in[0];
    const int*   scope    = (const int*)d_in[1];
    // d_in[2] = scope_rev (unused: flat row index == scope value)
    const float* Wa_pair  = (const float*)d_in[3];
    const float* Wa_score = (const float*)d_in[4];
    const float* W_proj   = (const float*)d_in[5];
    float* out = (float*)d_out;

    // outputs are accumulated via atomics across head-blocks -> zero the whole output
    (void)hipMemsetAsync(d_out, 0, (size_t)out_size, stream);

    // (head n, molecule): 256 blocks x 512 thr; 53.4 KB LDS
    dim3 grid(4, 64);
    atom_attn<<<grid, 512, 0, stream>>>(inputs, scope, Wa_pair, Wa_score,
                                        W_proj, out, out + 64 * 64);
}